// Round 1
// baseline (161.287 us; speedup 1.0000x reference)
//
#include <hip/hip_runtime.h>
#include <hip/hip_bf16.h>

#define HASH_BUCKETS 1024
#define D 256
#define BA 4096
#define BB 8192

// ---------------- hash kernel: hash_a (4096) and hash_b (8192) ----------------
__global__ __launch_bounds__(256) void hash_kernel(const int* __restrict__ ka,
                                                   const int* __restrict__ kb,
                                                   int* __restrict__ ha,
                                                   int* __restrict__ hb) {
    int i = blockIdx.x * 256 + threadIdx.x;
    if (i < BA) {
        int s = ka[i * 4] + ka[i * 4 + 1] + ka[i * 4 + 2] + ka[i * 4 + 3];
        ha[i] = s & (HASH_BUCKETS - 1);
    } else if (i < BA + BB) {
        int j = i - BA;
        int s = kb[j * 4] + kb[j * 4 + 1] + kb[j * 4 + 2] + kb[j * 4 + 3];
        hb[j] = s & (HASH_BUCKETS - 1);
    }
}

// -------- bucket mean kernel: 1 wave per bucket, ballot scan (deterministic) --------
__global__ __launch_bounds__(64) void bucket_kernel(const int* __restrict__ hb,
                                                    const float* __restrict__ tb,
                                                    float* __restrict__ bmean) {
    __shared__ int sh[BB];
    const int l = threadIdx.x;  // 0..63
    for (int j = l; j < BB; j += 64) sh[j] = hb[j];
    __syncthreads();
    const int h = blockIdx.x;
    float a0 = 0.f, a1 = 0.f, a2 = 0.f, a3 = 0.f;
    int cnt = 0;
    for (int base = 0; base < BB; base += 64) {
        unsigned long long m = __ballot(sh[base + l] == h);
        cnt += __popcll(m);
        while (m) {
            int j = base + (__ffsll((long long)m) - 1);
            m &= (m - 1);
            const float* row = tb + (size_t)j * D;
            a0 += row[l];
            a1 += row[l + 64];
            a2 += row[l + 128];
            a3 += row[l + 192];
        }
    }
    float inv = 1.0f / (float)max(cnt, 1);
    float* out = bmean + (size_t)h * D;
    out[l] = a0 * inv;
    out[l + 64] = a1 * inv;
    out[l + 128] = a2 * inv;
    out[l + 192] = a3 * inv;
}

// ---------------- bfused[c] = sum_k b2[k]*Wo[k][c] + bo[c] ----------------
__global__ __launch_bounds__(256) void bfused_kernel(const float* __restrict__ b2,
                                                     const float* __restrict__ Wo,
                                                     const float* __restrict__ bo,
                                                     float* __restrict__ bf) {
    int c = threadIdx.x;
    float acc = bo[c];
    for (int k = 0; k < 256; ++k) acc += b2[k] * Wo[k * 256 + c];
    bf[c] = acc;
}

// ---------------- tiled fp32 GEMM: C[M,N] = op(A[M,K] @ B[K,N] + bias) ----------------
// MODE 0: A gathered from [table_a | bucket_mean[hash_a]] (K must be 512), +bias, ReLU
// MODE 1: plain A, +bias
// MODE 2: plain A, no bias
#define TM 64
#define TN 64
#define TK 32
#define LPAD 68  // LDS row stride in floats

template <int MODE>
__global__ __launch_bounds__(256) void gemm_kernel(const float* __restrict__ A,
                                                   const float* __restrict__ ta,
                                                   const float* __restrict__ bmean,
                                                   const int* __restrict__ hasha,
                                                   const float* __restrict__ B,
                                                   const float* __restrict__ bias,
                                                   float* __restrict__ C,
                                                   int M, int N, int K) {
    __shared__ float As[TK * LPAD];  // As[k][m]
    __shared__ float Bs[TK * LPAD];  // Bs[k][n]
    const int tid = threadIdx.x;
    const int tx = tid & 15;
    const int ty = tid >> 4;
    const int bm = blockIdx.y * TM;
    const int bn = blockIdx.x * TN;

    float acc[4][4] = {};

    for (int k0 = 0; k0 < K; k0 += TK) {
        // ---- load A tile (64 m x 32 k), store transposed As[k][m] ----
        {
            const int kk = tid & 31;
            const int mbase = tid >> 5;  // 0..7
            const int gk = k0 + kk;
#pragma unroll
            for (int mi = 0; mi < 8; ++mi) {
                const int m = mi * 8 + mbase;
                const int grow = bm + m;
                float v;
                if (MODE == 0) {
                    v = (gk < 256) ? ta[(size_t)grow * 256 + gk]
                                   : bmean[(size_t)hasha[grow] * 256 + (gk - 256)];
                } else {
                    v = A[(size_t)grow * K + gk];
                }
                As[kk * LPAD + m] = v;
            }
        }
        // ---- load B tile (32 k x 64 n) ----
        {
            const int nn = tid & 63;
            const int kbase = tid >> 6;  // 0..3
#pragma unroll
            for (int ki = 0; ki < 8; ++ki) {
                const int k = ki * 4 + kbase;
                Bs[k * LPAD + nn] = B[(size_t)(k0 + k) * N + bn + nn];
            }
        }
        __syncthreads();
#pragma unroll
        for (int kk = 0; kk < TK; ++kk) {
            float4 a = *(const float4*)&As[kk * LPAD + ty * 4];
            float4 b = *(const float4*)&Bs[kk * LPAD + tx * 4];
            acc[0][0] += a.x * b.x; acc[0][1] += a.x * b.y; acc[0][2] += a.x * b.z; acc[0][3] += a.x * b.w;
            acc[1][0] += a.y * b.x; acc[1][1] += a.y * b.y; acc[1][2] += a.y * b.z; acc[1][3] += a.y * b.w;
            acc[2][0] += a.z * b.x; acc[2][1] += a.z * b.y; acc[2][2] += a.z * b.z; acc[2][3] += a.z * b.w;
            acc[3][0] += a.w * b.x; acc[3][1] += a.w * b.y; acc[3][2] += a.w * b.z; acc[3][3] += a.w * b.w;
        }
        __syncthreads();
    }

    // ---- epilogue ----
#pragma unroll
    for (int r = 0; r < 4; ++r) {
        const int row = bm + ty * 4 + r;
        const int col = bn + tx * 4;
        float4 v;
        float* pv = (float*)&v;
#pragma unroll
        for (int c = 0; c < 4; ++c) {
            float x = acc[r][c];
            if (MODE < 2) x += bias[col + c];
            if (MODE == 0) x = fmaxf(x, 0.0f);
            pv[c] = x;
        }
        *(float4*)&C[(size_t)row * N + col] = v;
    }
}

extern "C" void kernel_launch(void* const* d_in, const int* in_sizes, int n_in,
                              void* d_out, int out_size, void* d_ws, size_t ws_size,
                              hipStream_t stream) {
    const float* ta = (const float*)d_in[0];  // (4096, 256)
    const float* tb = (const float*)d_in[1];  // (8192, 256)
    const int* ka = (const int*)d_in[2];      // (4096, 4)
    const int* kb = (const int*)d_in[3];      // (8192, 4)
    const float* W1 = (const float*)d_in[4];  // (512, 512)
    const float* b1 = (const float*)d_in[5];  // (512,)
    const float* W2 = (const float*)d_in[6];  // (512, 256)
    const float* b2 = (const float*)d_in[7];  // (256,)
    const float* Wo = (const float*)d_in[8];  // (256, 256)
    const float* bo = (const float*)d_in[9];  // (256,)
    float* out = (float*)d_out;               // (4096, 256)

    char* ws = (char*)d_ws;
    int* ha = (int*)(ws + 0);                   // 4096 ints
    int* hb = (int*)(ws + 16384);               // 8192 ints
    float* bmean = (float*)(ws + 49152);        // 1024*256 f
    float* w2wo = (float*)(ws + 1097728);       // 512*256 f
    float* bfused = (float*)(ws + 1622016);     // 256 f
    float* hbuf = (float*)(ws + 1623040);       // 4096*512 f

    // 1. hashes
    hash_kernel<<<(BA + BB + 255) / 256, 256, 0, stream>>>(ka, kb, ha, hb);
    // 2. bucket means
    bucket_kernel<<<HASH_BUCKETS, 64, 0, stream>>>(hb, tb, bmean);
    // 3. W2 @ Wo  (512x256x256)
    {
        dim3 grid(256 / TN, 512 / TM);
        gemm_kernel<2><<<grid, 256, 0, stream>>>(W2, nullptr, nullptr, nullptr, Wo,
                                                 nullptr, w2wo, 512, 256, 256);
    }
    // 4. bfused = b2 @ Wo + bo
    bfused_kernel<<<1, 256, 0, stream>>>(b2, Wo, bo, bfused);
    // 5. h = relu([ta | bmean[ha]] @ W1 + b1)   (4096x512x512)
    {
        dim3 grid(512 / TN, BA / TM);
        gemm_kernel<0><<<grid, 256, 0, stream>>>(nullptr, ta, bmean, ha, W1, b1,
                                                 hbuf, BA, 512, 512);
    }
    // 6. out = h @ w2wo + bfused               (4096x256x512)
    {
        dim3 grid(256 / TN, BA / TM);
        gemm_kernel<1><<<grid, 256, 0, stream>>>(hbuf, nullptr, nullptr, nullptr, w2wo,
                                                 bfused, out, BA, 256, 512);
    }
}

// Round 2
// 57.087 us; speedup vs baseline: 2.8253x; 2.8253x over previous
//
#include <hip/hip_runtime.h>
#include <hip/hip_bf16.h>

#define HASH_BUCKETS 1024
#define D 256
#define BA 4096
#define BB 8192

typedef __attribute__((ext_vector_type(8))) short bf16x8;
typedef __attribute__((ext_vector_type(4))) float f32x4;

__device__ __forceinline__ short f2bf(float x) {
    union { float f; unsigned int u; } c;
    c.f = x;
    unsigned int lsb = (c.u >> 16) & 1u;
    c.u += 0x7fffu + lsb;  // round-to-nearest-even
    return (short)(c.u >> 16);
}

// ================= prep kernel: hashes + weight conversions + bfused =================
// blocks 0..63   : W1 (512x512) -> W1T bf16 (transposed)
// blocks 64..79  : Wo (256x256) -> WoT bf16 (transposed)
// blocks 80..87  : W2 (512x256) -> bf16 copy
// blocks 88..103 : hash_a (4096)
// blocks 104..135: hash_b (8192)
// block  136     : bfused = b2 @ Wo + bo (f32)
__global__ __launch_bounds__(256) void prep_kernel(
    const float* __restrict__ W1, const float* __restrict__ Wo,
    const float* __restrict__ W2, const float* __restrict__ b2,
    const float* __restrict__ bo, const int* __restrict__ ka,
    const int* __restrict__ kb, short* __restrict__ W1T,
    short* __restrict__ WoT, short* __restrict__ W2b,
    int* __restrict__ ha, int* __restrict__ hb, float* __restrict__ bfused) {
    __shared__ float tl[64][65];
    const int blk = blockIdx.x;
    const int t = threadIdx.x;
    if (blk < 64) {  // W1T
        const int tr = (blk >> 3) * 64, tc = (blk & 7) * 64;
        const int c = t & 63, r0 = t >> 6;
#pragma unroll
        for (int i = 0; i < 16; ++i) {
            int r = r0 + i * 4;
            tl[r][c] = W1[(size_t)(tr + r) * 512 + tc + c];
        }
        __syncthreads();
#pragma unroll
        for (int i = 0; i < 16; ++i) {
            int r = r0 + i * 4;
            W1T[(size_t)(tc + r) * 512 + tr + c] = f2bf(tl[c][r]);
        }
    } else if (blk < 80) {  // WoT
        const int b = blk - 64;
        const int tr = (b >> 2) * 64, tc = (b & 3) * 64;
        const int c = t & 63, r0 = t >> 6;
#pragma unroll
        for (int i = 0; i < 16; ++i) {
            int r = r0 + i * 4;
            tl[r][c] = Wo[(size_t)(tr + r) * 256 + tc + c];
        }
        __syncthreads();
#pragma unroll
        for (int i = 0; i < 16; ++i) {
            int r = r0 + i * 4;
            WoT[(size_t)(tc + r) * 256 + tr + c] = f2bf(tl[c][r]);
        }
    } else if (blk < 88) {  // W2 convert
        const int g = (blk - 80) * 256 + t;
#pragma unroll
        for (int i = 0; i < 16; ++i) {
            int e = g + i * 2048;
            float4 v = ((const float4*)W2)[e];
            short4 s;
            s.x = f2bf(v.x); s.y = f2bf(v.y); s.z = f2bf(v.z); s.w = f2bf(v.w);
            ((short4*)W2b)[e] = s;
        }
    } else if (blk < 104) {  // hash_a
        const int r = (blk - 88) * 256 + t;
        int s = ka[r * 4] + ka[r * 4 + 1] + ka[r * 4 + 2] + ka[r * 4 + 3];
        ha[r] = s & (HASH_BUCKETS - 1);
    } else if (blk < 136) {  // hash_b
        const int r = (blk - 104) * 256 + t;
        int s = kb[r * 4] + kb[r * 4 + 1] + kb[r * 4 + 2] + kb[r * 4 + 3];
        hb[r] = s & (HASH_BUCKETS - 1);
    } else {  // bfused
        float acc = bo[t];
        for (int k = 0; k < 256; ++k) acc += b2[k] * Wo[(size_t)k * 256 + t];
        bfused[t] = acc;
    }
}

// -------- bucket mean: 1 wave per bucket, ballot scan (deterministic), bf16 out --------
__global__ __launch_bounds__(64) void bucket_kernel(const int* __restrict__ hb,
                                                    const float* __restrict__ tb,
                                                    short* __restrict__ bmean) {
    __shared__ int sh[BB];
    const int l = threadIdx.x;
    for (int j = l; j < BB; j += 64) sh[j] = hb[j];
    __syncthreads();
    const int h = blockIdx.x;
    float a0 = 0.f, a1 = 0.f, a2 = 0.f, a3 = 0.f;
    int cnt = 0;
    for (int base = 0; base < BB; base += 64) {
        unsigned long long m = __ballot(sh[base + l] == h);
        cnt += __popcll(m);
        while (m) {
            int j = base + (__ffsll((long long)m) - 1);
            m &= (m - 1);
            const float* row = tb + (size_t)j * D;
            a0 += row[l];
            a1 += row[l + 64];
            a2 += row[l + 128];
            a3 += row[l + 192];
        }
    }
    float inv = 1.0f / (float)max(cnt, 1);
    short* out = bmean + (size_t)h * D;
    out[l] = f2bf(a0 * inv);
    out[l + 64] = f2bf(a1 * inv);
    out[l + 128] = f2bf(a2 * inv);
    out[l + 192] = f2bf(a3 * inv);
}

// ---------- gather: A1[r] = [bf16(ta[r]) | bmean[ha[r]]]  (4096 x 512) ----------
__global__ __launch_bounds__(256) void gather_kernel(const float* __restrict__ ta,
                                                     const short* __restrict__ bmean,
                                                     const int* __restrict__ ha,
                                                     short* __restrict__ A1) {
    const int r = blockIdx.x * 4 + (threadIdx.x >> 6);
    const int l = threadIdx.x & 63;
    float4 v = *(const float4*)&ta[(size_t)r * 256 + 4 * l];
    short4 s;
    s.x = f2bf(v.x); s.y = f2bf(v.y); s.z = f2bf(v.z); s.w = f2bf(v.w);
    *(short4*)&A1[(size_t)r * 512 + 4 * l] = s;
    const int h = ha[r];
    *(short4*)&A1[(size_t)r * 512 + 256 + 4 * l] = *(const short4*)&bmean[(size_t)h * 256 + 4 * l];
}

// =============== MFMA bf16 GEMM: C[M,N] = op(A[M,K] @ Bt[N,K]^T) ===============
// MODE 0: +bias, ReLU, bf16 out [M][N]
// MODE 1: +bias, f32 out [M][N]
// MODE 2: no bias, bf16 out TRANSPOSED [N][M]
template <int BM, int BN, int MODE>
__global__ __launch_bounds__(256) void mgemm(const short* __restrict__ A,
                                             const short* __restrict__ Bt,
                                             const float* __restrict__ bias,
                                             void* __restrict__ Cv,
                                             int M, int N, int K) {
    constexpr int BK = 32;
    constexpr int LDA = BK + 8;  // 40 shorts = 80B row stride -> <=2-way conflicts
    constexpr int WSM = BM / 2, WSN = BN / 2;
    constexpr int MF = WSM / 16, NF = WSN / 16;
    __shared__ short As[BM * LDA];
    __shared__ short Bs[BN * LDA];
    const int tid = threadIdx.x;
    const int lane = tid & 63;
    const int wid = tid >> 6;
    const int wm = wid >> 1, wn = wid & 1;
    const int bm = blockIdx.y * BM, bn = blockIdx.x * BN;

    f32x4 acc[MF][NF] = {};

    const int r_s = tid >> 2;            // staging row
    const int koff = (tid & 3) * 8;      // staging k offset
    const int kf = (lane >> 4) * 8;      // fragment k offset
    const int lr = lane & 15;            // fragment row/col within 16

    for (int k0 = 0; k0 < K; k0 += BK) {
#pragma unroll
        for (int i = 0; i < BM / 64; ++i) {
            int r = i * 64 + r_s;
            *(bf16x8*)&As[r * LDA + koff] = *(const bf16x8*)&A[(size_t)(bm + r) * K + k0 + koff];
        }
#pragma unroll
        for (int i = 0; i < BN / 64; ++i) {
            int r = i * 64 + r_s;
            *(bf16x8*)&Bs[r * LDA + koff] = *(const bf16x8*)&Bt[(size_t)(bn + r) * K + k0 + koff];
        }
        __syncthreads();
        bf16x8 af[MF], bfr[NF];
#pragma unroll
        for (int mf = 0; mf < MF; ++mf)
            af[mf] = *(const bf16x8*)&As[(wm * WSM + mf * 16 + lr) * LDA + kf];
#pragma unroll
        for (int nf = 0; nf < NF; ++nf)
            bfr[nf] = *(const bf16x8*)&Bs[(wn * WSN + nf * 16 + lr) * LDA + kf];
#pragma unroll
        for (int mf = 0; mf < MF; ++mf)
#pragma unroll
            for (int nf = 0; nf < NF; ++nf)
                acc[mf][nf] = __builtin_amdgcn_mfma_f32_16x16x32_bf16(af[mf], bfr[nf], acc[mf][nf], 0, 0, 0);
        __syncthreads();
    }

    // epilogue: D element i -> row (lane>>4)*4+i, col lane&15
#pragma unroll
    for (int mf = 0; mf < MF; ++mf) {
#pragma unroll
        for (int nf = 0; nf < NF; ++nf) {
            const int col = bn + wn * WSN + nf * 16 + lr;
            const int rbase = bm + wm * WSM + mf * 16 + ((lane >> 4) << 2);
            float bv = (MODE == 2) ? 0.f : bias[col];
#pragma unroll
            for (int i = 0; i < 4; ++i) {
                float x = acc[mf][nf][i];
                const int row = rbase + i;
                if (MODE == 0) {
                    x = fmaxf(x + bv, 0.f);
                    ((short*)Cv)[(size_t)row * N + col] = f2bf(x);
                } else if (MODE == 1) {
                    ((float*)Cv)[(size_t)row * N + col] = x + bv;
                } else {
                    ((short*)Cv)[(size_t)col * M + row] = f2bf(x);
                }
            }
        }
    }
}

extern "C" void kernel_launch(void* const* d_in, const int* in_sizes, int n_in,
                              void* d_out, int out_size, void* d_ws, size_t ws_size,
                              hipStream_t stream) {
    const float* ta = (const float*)d_in[0];
    const float* tb = (const float*)d_in[1];
    const int* ka = (const int*)d_in[2];
    const int* kb = (const int*)d_in[3];
    const float* W1 = (const float*)d_in[4];
    const float* b1 = (const float*)d_in[5];
    const float* W2 = (const float*)d_in[6];
    const float* b2 = (const float*)d_in[7];
    const float* Wo = (const float*)d_in[8];
    const float* bo = (const float*)d_in[9];
    float* out = (float*)d_out;

    char* ws = (char*)d_ws;
    int* ha = (int*)(ws + 0);                 // 16 KB
    int* hb = (int*)(ws + 16384);             // 32 KB
    short* bmean = (short*)(ws + 49152);      // 512 KB (bf16 1024x256)
    short* A1 = (short*)(ws + 573440);        // 4 MB (bf16 4096x512)
    short* W1T = (short*)(ws + 4767744);      // 512 KB (bf16 512x512 T)
    short* w2woT = (short*)(ws + 5292032);    // 256 KB (bf16 256x512)
    float* bfused = (float*)(ws + 5554176);   // 1 KB
    short* hbuf = (short*)(ws + 5555200);     // 4 MB (bf16 4096x512)
    // W2b / WoT only live until G0, which runs before hbuf is written -> alias hbuf
    short* W2b = (short*)(ws + 5555200);      // 256 KB
    short* WoT = (short*)(ws + 5817344);      // 128 KB

    // 1. prep: hashes, weight conversions/transposes, bfused
    prep_kernel<<<137, 256, 0, stream>>>(W1, Wo, W2, b2, bo, ka, kb,
                                         W1T, WoT, W2b, ha, hb, bfused);
    // 2. bucket means (bf16)
    bucket_kernel<<<HASH_BUCKETS, 64, 0, stream>>>(hb, tb, bmean);
    // 3. G0: w2woT = (W2 @ Wo)^T   M=512 N=256 K=256, transposed bf16 out
    {
        dim3 grid(256 / 64, 512 / 64);
        mgemm<64, 64, 2><<<grid, 256, 0, stream>>>(W2b, WoT, nullptr, w2woT, 512, 256, 256);
    }
    // 4. gather A1 = [ta | bmean[ha]]
    gather_kernel<<<BA / 4, 256, 0, stream>>>(ta, bmean, ha, A1);
    // 5. G1: hbuf = relu(A1 @ W1 + b1)   M=4096 N=512 K=512, bf16 out
    {
        dim3 grid(512 / 64, BA / 64);
        mgemm<64, 64, 0><<<grid, 256, 0, stream>>>(A1, W1T, b1, hbuf, BA, 512, 512);
    }
    // 6. G2: out = hbuf @ w2wo + bfused   M=4096 N=256 K=512, f32 out
    {
        dim3 grid(256 / 64, BA / 64);
        mgemm<64, 64, 1><<<grid, 256, 0, stream>>>(hbuf, w2woT, bfused, out, BA, 256, 512);
    }
}

// Round 4
// 37.579 us; speedup vs baseline: 4.2919x; 1.5191x over previous
//
#include <hip/hip_runtime.h>
#include <hip/hip_bf16.h>

#define HASH_BUCKETS 1024
#define BA 4096
#define BB 8192

typedef __attribute__((ext_vector_type(8))) short bf16x8;
typedef __attribute__((ext_vector_type(4))) float f32x4;

__device__ __forceinline__ short f2bf(float x) {
    union { float f; unsigned int u; } c;
    c.f = x;
    unsigned int lsb = (c.u >> 16) & 1u;
    c.u += 0x7fffu + lsb;  // RNE
    return (short)(c.u >> 16);
}

__device__ __forceinline__ void gl_lds16(const void* g, void* l) {
    __builtin_amdgcn_global_load_lds((const __attribute__((address_space(1))) void*)g,
                                     (__attribute__((address_space(3))) void*)l, 16, 0, 0);
}

// ================= mega prep kernel =================
// blocks 0..63    : W1 (512x512 f32) -> W1T bf16 [n][k]
// blocks 64..95   : w2woT[n][k] = bf16((W2 @ Wo)[k][n])  (fp32 mini-GEMM)
// blocks 96..159  : ta f32 -> tab bf16
// blocks 160..175 : hash_a
// block  176      : bfused = b2 @ Wo + bo (f32)
// blocks 177..1200: bucket means (1 block per bucket; self-computes hash_b)
__global__ __launch_bounds__(256) void prep_kernel(
    const float* __restrict__ W1, const float* __restrict__ Wo,
    const float* __restrict__ W2, const float* __restrict__ b2,
    const float* __restrict__ bo, const float* __restrict__ ta,
    const float* __restrict__ tb, const int* __restrict__ ka,
    const int* __restrict__ kb, short* __restrict__ W1T,
    short* __restrict__ w2woT, short* __restrict__ tab,
    int* __restrict__ ha, float* __restrict__ bfused,
    short* __restrict__ bmean) {
    __shared__ __align__(16) char smem[36896];
    const int blk = blockIdx.x;
    const int t = threadIdx.x;
    if (blk < 64) {  // ---- W1T transpose ----
        float(*tl)[65] = (float(*)[65])smem;
        const int tr = (blk >> 3) * 64, tc = (blk & 7) * 64;
        const int c = t & 63, r0 = t >> 6;
#pragma unroll
        for (int i = 0; i < 16; ++i) {
            int r = r0 + i * 4;
            tl[r][c] = W1[(size_t)(tr + r) * 512 + tc + c];
        }
        __syncthreads();
#pragma unroll
        for (int i = 0; i < 16; ++i) {
            int r = r0 + i * 4;
            W1T[(size_t)(tc + r) * 512 + tr + c] = f2bf(tl[c][r]);
        }
    } else if (blk < 96) {  // ---- w2woT mini-GEMM: C[k][n] = sum_c W2[k][c]*Wo[c][n] ----
        float* As = (float*)smem;            // [32][68]
        float* Bs = (float*)(smem + 8704);   // [32][68]
        const int b = blk - 64;
        const int bn = (b & 3) * 64;
        const int bm = (b >> 2) * 64;
        const int tx = t & 15, ty = t >> 4;
        float acc[4][4] = {};
        for (int c0 = 0; c0 < 256; c0 += 32) {
            {
                const int cc = t & 31, mb = t >> 5;
#pragma unroll
                for (int mi = 0; mi < 8; ++mi) {
                    int m = mi * 8 + mb;
                    As[cc * 68 + m] = W2[(size_t)(bm + m) * 256 + c0 + cc];
                }
            }
            {
                const int nn = t & 63, cb = t >> 6;
#pragma unroll
                for (int ci = 0; ci < 8; ++ci) {
                    int c = ci * 4 + cb;
                    Bs[c * 68 + nn] = Wo[(size_t)(c0 + c) * 256 + bn + nn];
                }
            }
            __syncthreads();
#pragma unroll
            for (int cc = 0; cc < 32; ++cc) {
                float4 a = *(const float4*)&As[cc * 68 + ty * 4];
                float4 bv = *(const float4*)&Bs[cc * 68 + tx * 4];
                acc[0][0] += a.x * bv.x; acc[0][1] += a.x * bv.y; acc[0][2] += a.x * bv.z; acc[0][3] += a.x * bv.w;
                acc[1][0] += a.y * bv.x; acc[1][1] += a.y * bv.y; acc[1][2] += a.y * bv.z; acc[1][3] += a.y * bv.w;
                acc[2][0] += a.z * bv.x; acc[2][1] += a.z * bv.y; acc[2][2] += a.z * bv.z; acc[2][3] += a.z * bv.w;
                acc[3][0] += a.w * bv.x; acc[3][1] += a.w * bv.y; acc[3][2] += a.w * bv.z; acc[3][3] += a.w * bv.w;
            }
            __syncthreads();
        }
#pragma unroll
        for (int r = 0; r < 4; ++r)
#pragma unroll
            for (int c = 0; c < 4; ++c) {
                int k = bm + ty * 4 + r, n = bn + tx * 4 + c;
                w2woT[(size_t)n * 512 + k] = f2bf(acc[r][c]);
            }
    } else if (blk < 160) {  // ---- tab convert ----
        const int b = blk - 96;
#pragma unroll
        for (int i = 0; i < 16; ++i) {
            int e = b * 4096 + i * 256 + t;
            float4 v = ((const float4*)ta)[e];
            short4 s;
            s.x = f2bf(v.x); s.y = f2bf(v.y); s.z = f2bf(v.z); s.w = f2bf(v.w);
            ((short4*)tab)[e] = s;
        }
    } else if (blk < 176) {  // ---- hash_a ----
        const int r = (blk - 160) * 256 + t;
        int4 k4 = ((const int4*)ka)[r];
        ha[r] = (k4.x + k4.y + k4.z + k4.w) & (HASH_BUCKETS - 1);
    } else if (blk == 176) {  // ---- bfused ----
        float acc = bo[t];
        for (int k = 0; k < 256; ++k) acc += b2[k] * Wo[(size_t)k * 256 + t];
        bfused[t] = acc;
    } else {  // ---- bucket mean: bucket h = blk-177 ----
        int* sh = (int*)smem;                    // 8192 ints
        float* part = (float*)(smem + 32768);    // 4*256 floats
        int* pcnt = (int*)(smem + 36864);        // 4 ints
        const int h = blk - 177;
        const int w = t >> 6, l = t & 63;
#pragma unroll 4
        for (int i = 0; i < 32; ++i) {
            int r = i * 256 + t;
            int4 k4 = ((const int4*)kb)[r];
            sh[r] = (k4.x + k4.y + k4.z + k4.w) & (HASH_BUCKETS - 1);
        }
        __syncthreads();
        float a0 = 0.f, a1 = 0.f, a2 = 0.f, a3 = 0.f;
        int cnt = 0;
#pragma unroll 4
        for (int it = 0; it < 32; ++it) {
            int base = w * 2048 + it * 64;
            unsigned long long m = __ballot(sh[base + l] == h);
            cnt += __popcll(m);
            while (m) {
                int j = base + (__ffsll((long long)m) - 1);
                m &= (m - 1);
                const float* row = tb + (size_t)j * 256;
                a0 += row[l];
                a1 += row[l + 64];
                a2 += row[l + 128];
                a3 += row[l + 192];
            }
        }
        part[w * 256 + l] = a0;
        part[w * 256 + l + 64] = a1;
        part[w * 256 + l + 128] = a2;
        part[w * 256 + l + 192] = a3;
        if (l == 0) pcnt[w] = cnt;
        __syncthreads();
        float s = part[t] + part[256 + t] + part[512 + t] + part[768 + t];
        int c = pcnt[0] + pcnt[1] + pcnt[2] + pcnt[3];
        bmean[(size_t)h * 256 + t] = f2bf(s / (float)max(c, 1));
    }
}

// =============== MFMA bf16 GEMM, 64x64 tile, BK=32, global_load_lds staging ===============
// MODE 0: A gathered inline from [tab | bmean[ha]] (K=512), +bias, ReLU, bf16 out
// MODE 1: plain bf16 A, +bias, f32 out
template <int MODE>
__global__ __launch_bounds__(256) void mfgemm(const short* __restrict__ A,
                                              const short* __restrict__ Bt,
                                              const short* __restrict__ tab,
                                              const short* __restrict__ bmean,
                                              const int* __restrict__ ha,
                                              const float* __restrict__ bias,
                                              void* __restrict__ Cv,
                                              int M, int N, int K) {
    __shared__ short As[64 * 32];  // [row][k], linear (global_load_lds dest)
    __shared__ short Bs[64 * 32];  // [n][k], linear
    const int tid = threadIdx.x;
    const int l = tid & 63, w = tid >> 6;
    const int wm = w >> 1, wn = w & 1;
    const int bm = blockIdx.y * 64, bn = blockIdx.x * 64;

    const int srow = l >> 2;        // 0..15: row within this wave's 16-row chunk
    const int skoff = (l & 3) * 8;  // 0/8/16/24 shorts
    const int arow = bm + w * 16 + srow;
    const int brow = bn + w * 16 + srow;
    int ha_r = 0;
    if (MODE == 0) ha_r = ha[arow];
    short* a_dst = &As[(w * 16) * 32];  // wave-uniform; HW adds lane*16B
    short* b_dst = &Bs[(w * 16) * 32];

    const int lr = l & 15, kf = (l >> 4) * 8;
    f32x4 acc[2][2] = {};

    for (int k0 = 0; k0 < K; k0 += 32) {
        const short* asrc;
        if (MODE == 0)
            asrc = (k0 < 256) ? &tab[(size_t)arow * 256 + k0 + skoff]
                              : &bmean[(size_t)ha_r * 256 + (k0 - 256) + skoff];
        else
            asrc = &A[(size_t)arow * K + k0 + skoff];
        gl_lds16(asrc, a_dst);
        gl_lds16(&Bt[(size_t)brow * K + k0 + skoff], b_dst);
        __syncthreads();
        bf16x8 af0 = *(const bf16x8*)&As[(wm * 32 + lr) * 32 + kf];
        bf16x8 af1 = *(const bf16x8*)&As[(wm * 32 + 16 + lr) * 32 + kf];
        bf16x8 bf0 = *(const bf16x8*)&Bs[(wn * 32 + lr) * 32 + kf];
        bf16x8 bf1 = *(const bf16x8*)&Bs[(wn * 32 + 16 + lr) * 32 + kf];
        acc[0][0] = __builtin_amdgcn_mfma_f32_16x16x32_bf16(af0, bf0, acc[0][0], 0, 0, 0);
        acc[0][1] = __builtin_amdgcn_mfma_f32_16x16x32_bf16(af0, bf1, acc[0][1], 0, 0, 0);
        acc[1][0] = __builtin_amdgcn_mfma_f32_16x16x32_bf16(af1, bf0, acc[1][0], 0, 0, 0);
        acc[1][1] = __builtin_amdgcn_mfma_f32_16x16x32_bf16(af1, bf1, acc[1][1], 0, 0, 0);
        __syncthreads();
    }

#pragma unroll
    for (int mf = 0; mf < 2; ++mf)
#pragma unroll
        for (int nf = 0; nf < 2; ++nf) {
            const int col = bn + wn * 32 + nf * 16 + lr;
            const int rbase = bm + wm * 32 + mf * 16 + ((l >> 4) << 2);
            const float bv = bias[col];
#pragma unroll
            for (int i = 0; i < 4; ++i) {
                const float x = acc[mf][nf][i] + bv;
                const int row = rbase + i;
                if (MODE == 0)
                    ((short*)Cv)[(size_t)row * N + col] = f2bf(fmaxf(x, 0.f));
                else
                    ((float*)Cv)[(size_t)row * N + col] = x;
            }
        }
}

extern "C" void kernel_launch(void* const* d_in, const int* in_sizes, int n_in,
                              void* d_out, int out_size, void* d_ws, size_t ws_size,
                              hipStream_t stream) {
    const float* ta = (const float*)d_in[0];
    const float* tb = (const float*)d_in[1];
    const int* ka = (const int*)d_in[2];
    const int* kb = (const int*)d_in[3];
    const float* W1 = (const float*)d_in[4];
    const float* b1 = (const float*)d_in[5];
    const float* W2 = (const float*)d_in[6];
    const float* b2 = (const float*)d_in[7];
    const float* Wo = (const float*)d_in[8];
    const float* bo = (const float*)d_in[9];
    float* out = (float*)d_out;

    char* ws = (char*)d_ws;
    int* ha = (int*)(ws + 0);                // 16 KB
    short* bmean = (short*)(ws + 16384);     // 512 KB bf16 1024x256
    short* tab = (short*)(ws + 540672);      // 2 MB  bf16 4096x256
    short* W1T = (short*)(ws + 2637824);     // 512 KB bf16 512x512
    short* w2woT = (short*)(ws + 3162112);   // 256 KB bf16 256x512
    float* bfused = (float*)(ws + 3424256);  // 1 KB
    short* hbuf = (short*)(ws + 3425280);    // 4 MB  bf16 4096x512

    // 1. mega prep: W1T, w2woT, tab, ha, bfused, bucket means
    prep_kernel<<<1201, 256, 0, stream>>>(W1, Wo, W2, b2, bo, ta, tb, ka, kb,
                                          W1T, w2woT, tab, ha, bfused, bmean);
    // 2. G1: hbuf = relu([tab | bmean[ha]] @ W1 + b1)   M=4096 N=512 K=512
    mfgemm<0><<<dim3(8, 64), 256, 0, stream>>>(nullptr, W1T, tab, bmean, ha, b1,
                                               hbuf, BA, 512, 512);
    // 3. G2: out = hbuf @ w2wo + bfused                 M=4096 N=256 K=512
    mfgemm<1><<<dim3(4, 64), 256, 0, stream>>>(hbuf, w2woT, nullptr, nullptr, nullptr,
                                               bfused, out, BA, 256, 512);
}

// Round 5
// 35.443 us; speedup vs baseline: 4.5507x; 1.0603x over previous
//
#include <hip/hip_runtime.h>
#include <hip/hip_bf16.h>

#define HASH_BUCKETS 1024
#define BA 4096
#define BB 8192

typedef __attribute__((ext_vector_type(8))) short bf16x8;
typedef __attribute__((ext_vector_type(4))) float f32x4;

__device__ __forceinline__ short f2bf(float x) {
    union { float f; unsigned int u; } c;
    c.f = x;
    unsigned int lsb = (c.u >> 16) & 1u;
    c.u += 0x7fffu + lsb;  // RNE
    return (short)(c.u >> 16);
}

__device__ __forceinline__ void gl_lds16(const void* g, void* l) {
    __builtin_amdgcn_global_load_lds((const __attribute__((address_space(1))) void*)g,
                                     (__attribute__((address_space(3))) void*)l, 16, 0, 0);
}

// ================= mega prep kernel (unchanged from round 4, verified) =================
// blocks 0..63    : W1 (512x512 f32) -> W1T bf16 [n][k]
// blocks 64..95   : w2woT[n][k] = bf16((W2 @ Wo)[k][n])  (fp32 mini-GEMM)
// blocks 96..159  : ta f32 -> tab bf16
// blocks 160..175 : hash_a
// block  176      : bfused = b2 @ Wo + bo (f32)
// blocks 177..1200: bucket means (1 block per bucket; self-computes hash_b)
__global__ __launch_bounds__(256) void prep_kernel(
    const float* __restrict__ W1, const float* __restrict__ Wo,
    const float* __restrict__ W2, const float* __restrict__ b2,
    const float* __restrict__ bo, const float* __restrict__ ta,
    const float* __restrict__ tb, const int* __restrict__ ka,
    const int* __restrict__ kb, short* __restrict__ W1T,
    short* __restrict__ w2woT, short* __restrict__ tab,
    int* __restrict__ ha, float* __restrict__ bfused,
    short* __restrict__ bmean) {
    __shared__ __align__(16) char smem[36896];
    const int blk = blockIdx.x;
    const int t = threadIdx.x;
    if (blk < 64) {  // ---- W1T transpose ----
        float(*tl)[65] = (float(*)[65])smem;
        const int tr = (blk >> 3) * 64, tc = (blk & 7) * 64;
        const int c = t & 63, r0 = t >> 6;
#pragma unroll
        for (int i = 0; i < 16; ++i) {
            int r = r0 + i * 4;
            tl[r][c] = W1[(size_t)(tr + r) * 512 + tc + c];
        }
        __syncthreads();
#pragma unroll
        for (int i = 0; i < 16; ++i) {
            int r = r0 + i * 4;
            W1T[(size_t)(tc + r) * 512 + tr + c] = f2bf(tl[c][r]);
        }
    } else if (blk < 96) {  // ---- w2woT mini-GEMM: C[k][n] = sum_c W2[k][c]*Wo[c][n] ----
        float* As = (float*)smem;           // [32][68]
        float* Bs = (float*)(smem + 8704);  // [32][68]
        const int b = blk - 64;
        const int bn = (b & 3) * 64;
        const int bm = (b >> 2) * 64;
        const int tx = t & 15, ty = t >> 4;
        float acc[4][4] = {};
        for (int c0 = 0; c0 < 256; c0 += 32) {
            {
                const int cc = t & 31, mb = t >> 5;
#pragma unroll
                for (int mi = 0; mi < 8; ++mi) {
                    int m = mi * 8 + mb;
                    As[cc * 68 + m] = W2[(size_t)(bm + m) * 256 + c0 + cc];
                }
            }
            {
                const int nn = t & 63, cb = t >> 6;
#pragma unroll
                for (int ci = 0; ci < 8; ++ci) {
                    int c = ci * 4 + cb;
                    Bs[c * 68 + nn] = Wo[(size_t)(c0 + c) * 256 + bn + nn];
                }
            }
            __syncthreads();
#pragma unroll
            for (int cc = 0; cc < 32; ++cc) {
                float4 a = *(const float4*)&As[cc * 68 + ty * 4];
                float4 bv = *(const float4*)&Bs[cc * 68 + tx * 4];
                acc[0][0] += a.x * bv.x; acc[0][1] += a.x * bv.y; acc[0][2] += a.x * bv.z; acc[0][3] += a.x * bv.w;
                acc[1][0] += a.y * bv.x; acc[1][1] += a.y * bv.y; acc[1][2] += a.y * bv.z; acc[1][3] += a.y * bv.w;
                acc[2][0] += a.z * bv.x; acc[2][1] += a.z * bv.y; acc[2][2] += a.z * bv.z; acc[2][3] += a.z * bv.w;
                acc[3][0] += a.w * bv.x; acc[3][1] += a.w * bv.y; acc[3][2] += a.w * bv.z; acc[3][3] += a.w * bv.w;
            }
            __syncthreads();
        }
#pragma unroll
        for (int r = 0; r < 4; ++r)
#pragma unroll
            for (int c = 0; c < 4; ++c) {
                int k = bm + ty * 4 + r, n = bn + tx * 4 + c;
                w2woT[(size_t)n * 512 + k] = f2bf(acc[r][c]);
            }
    } else if (blk < 160) {  // ---- tab convert ----
        const int b = blk - 96;
#pragma unroll
        for (int i = 0; i < 16; ++i) {
            int e = b * 4096 + i * 256 + t;
            float4 v = ((const float4*)ta)[e];
            short4 s;
            s.x = f2bf(v.x); s.y = f2bf(v.y); s.z = f2bf(v.z); s.w = f2bf(v.w);
            ((short4*)tab)[e] = s;
        }
    } else if (blk < 176) {  // ---- hash_a ----
        const int r = (blk - 160) * 256 + t;
        int4 k4 = ((const int4*)ka)[r];
        ha[r] = (k4.x + k4.y + k4.z + k4.w) & (HASH_BUCKETS - 1);
    } else if (blk == 176) {  // ---- bfused ----
        float acc = bo[t];
        for (int k = 0; k < 256; ++k) acc += b2[k] * Wo[(size_t)k * 256 + t];
        bfused[t] = acc;
    } else {  // ---- bucket mean: bucket h = blk-177 ----
        int* sh = (int*)smem;                  // 8192 ints
        float* part = (float*)(smem + 32768);  // 4*256 floats
        int* pcnt = (int*)(smem + 36864);      // 4 ints
        const int h = blk - 177;
        const int w = t >> 6, l = t & 63;
#pragma unroll 4
        for (int i = 0; i < 32; ++i) {
            int r = i * 256 + t;
            int4 k4 = ((const int4*)kb)[r];
            sh[r] = (k4.x + k4.y + k4.z + k4.w) & (HASH_BUCKETS - 1);
        }
        __syncthreads();
        float a0 = 0.f, a1 = 0.f, a2 = 0.f, a3 = 0.f;
        int cnt = 0;
#pragma unroll 4
        for (int it = 0; it < 32; ++it) {
            int base = w * 2048 + it * 64;
            unsigned long long m = __ballot(sh[base + l] == h);
            cnt += __popcll(m);
            while (m) {
                int j = base + (__ffsll((long long)m) - 1);
                m &= (m - 1);
                const float* row = tb + (size_t)j * 256;
                a0 += row[l];
                a1 += row[l + 64];
                a2 += row[l + 128];
                a3 += row[l + 192];
            }
        }
        part[w * 256 + l] = a0;
        part[w * 256 + l + 64] = a1;
        part[w * 256 + l + 128] = a2;
        part[w * 256 + l + 192] = a3;
        if (l == 0) pcnt[w] = cnt;
        __syncthreads();
        float s = part[t] + part[256 + t] + part[512 + t] + part[768 + t];
        int c = pcnt[0] + pcnt[1] + pcnt[2] + pcnt[3];
        bmean[(size_t)h * 256 + t] = f2bf(s / (float)max(c, 1));
    }
}

// ======== MFMA bf16 GEMM v2: 64x64 tile, BK=64, double-buffered 2-phase pipeline ========
// LDS layout: [row][k16^(row&7)] (both-sides XOR swizzle; gl_lds dest linear,
// source k pre-swizzled, ds_read applies same XOR) -> conflict-free b128 reads.
// MODE 0: A gathered inline from [tab | bmean[ha]] (K=512), +bias, ReLU, bf16 out
// MODE 1: plain bf16 A, +bias, f32 out
template <int MODE>
__global__ __launch_bounds__(256) void mfgemm(const short* __restrict__ A,
                                              const short* __restrict__ Bt,
                                              const short* __restrict__ tab,
                                              const short* __restrict__ bmean,
                                              const int* __restrict__ ha,
                                              const float* __restrict__ bias,
                                              void* __restrict__ Cv,
                                              int M, int N, int K) {
    __shared__ short As[2][64 * 64];  // 8 KB per buffer
    __shared__ short Bs[2][64 * 64];
    const int tid = threadIdx.x;
    const int l = tid & 63, w = tid >> 6;
    const int wm = w >> 1, wn = w & 1;
    const int bm = blockIdx.y * 64, bn = blockIdx.x * 64;

    // staging geometry: call c in {0,1}: q=w*2+c covers rows 8q..8q+7 of the tile.
    // lane l -> row 8q + (l>>3), 16B-unit k16 = l&7. Source k pre-swizzled by row&7.
    const int r0 = (w * 2 + 0) * 8 + (l >> 3);
    const int r1 = (w * 2 + 1) * 8 + (l >> 3);
    const int sk0 = ((l & 7) ^ (r0 & 7)) * 8;  // swizzled k offset (shorts)
    const int sk1 = ((l & 7) ^ (r1 & 7)) * 8;
    const int arow0 = bm + r0, arow1 = bm + r1;
    const int brow0 = bn + r0, brow1 = bn + r1;
    int ha0 = 0, ha1 = 0;
    if (MODE == 0) { ha0 = ha[arow0]; ha1 = ha[arow1]; }
    const int dst0 = (w * 2 + 0) * 512;  // 8 rows * 64 shorts
    const int dst1 = (w * 2 + 1) * 512;

    const int lr = l & 15;  // fragment row within 16
    const int g = l >> 4;   // k-subgroup 0..3
    f32x4 acc[2][2] = {};

    auto STAGE = [&](int nb, int kt) {
        const int k0 = kt * 64;
        const short *as0, *as1;
        if (MODE == 0) {
            if (k0 < 256) {
                as0 = &tab[(size_t)arow0 * 256 + k0 + sk0];
                as1 = &tab[(size_t)arow1 * 256 + k0 + sk1];
            } else {
                as0 = &bmean[(size_t)ha0 * 256 + (k0 - 256) + sk0];
                as1 = &bmean[(size_t)ha1 * 256 + (k0 - 256) + sk1];
            }
        } else {
            as0 = &A[(size_t)arow0 * K + k0 + sk0];
            as1 = &A[(size_t)arow1 * K + k0 + sk1];
        }
        gl_lds16(as0, &As[nb][dst0]);
        gl_lds16(as1, &As[nb][dst1]);
        gl_lds16(&Bt[(size_t)brow0 * K + k0 + sk0], &Bs[nb][dst0]);
        gl_lds16(&Bt[(size_t)brow1 * K + k0 + sk1], &Bs[nb][dst1]);
    };

    auto COMPUTE = [&](int nb) {
        const short* ab = &As[nb][0];
        const short* bb = &Bs[nb][0];
        bf16x8 af[2][2], bfr[2][2];
#pragma unroll
        for (int mf = 0; mf < 2; ++mf) {
            const int rr = wm * 32 + mf * 16 + lr;
#pragma unroll
            for (int ks = 0; ks < 2; ++ks)
                af[mf][ks] = *(const bf16x8*)&ab[rr * 64 + (((ks * 4 + g) ^ (lr & 7)) * 8)];
        }
#pragma unroll
        for (int nf = 0; nf < 2; ++nf) {
            const int rr = wn * 32 + nf * 16 + lr;
#pragma unroll
            for (int ks = 0; ks < 2; ++ks)
                bfr[nf][ks] = *(const bf16x8*)&bb[rr * 64 + (((ks * 4 + g) ^ (lr & 7)) * 8)];
        }
#pragma unroll
        for (int ks = 0; ks < 2; ++ks)
#pragma unroll
            for (int mf = 0; mf < 2; ++mf)
#pragma unroll
                for (int nf = 0; nf < 2; ++nf)
                    acc[mf][nf] = __builtin_amdgcn_mfma_f32_16x16x32_bf16(
                        af[mf][ks], bfr[nf][ks], acc[mf][nf], 0, 0, 0);
    };

    const int nt = K >> 6;
    STAGE(0, 0);
    asm volatile("s_waitcnt vmcnt(0)" ::: "memory");
    __syncthreads();
    for (int t = 0; t < nt; ++t) {
        const int cur = t & 1;
        if (t + 1 < nt) STAGE(cur ^ 1, t + 1);
        COMPUTE(cur);
        asm volatile("s_waitcnt vmcnt(0)" ::: "memory");
        __syncthreads();
    }

    // epilogue (verified): D elem i -> row (l>>4)*4+i, col lr
#pragma unroll
    for (int mf = 0; mf < 2; ++mf)
#pragma unroll
        for (int nf = 0; nf < 2; ++nf) {
            const int col = bn + wn * 32 + nf * 16 + lr;
            const int rbase = bm + wm * 32 + mf * 16 + ((l >> 4) << 2);
            const float bv = bias[col];
#pragma unroll
            for (int i = 0; i < 4; ++i) {
                const float x = acc[mf][nf][i] + bv;
                const int row = rbase + i;
                if (MODE == 0)
                    ((short*)Cv)[(size_t)row * N + col] = f2bf(fmaxf(x, 0.f));
                else
                    ((float*)Cv)[(size_t)row * N + col] = x;
            }
        }
}

extern "C" void kernel_launch(void* const* d_in, const int* in_sizes, int n_in,
                              void* d_out, int out_size, void* d_ws, size_t ws_size,
                              hipStream_t stream) {
    const float* ta = (const float*)d_in[0];
    const float* tb = (const float*)d_in[1];
    const int* ka = (const int*)d_in[2];
    const int* kb = (const int*)d_in[3];
    const float* W1 = (const float*)d_in[4];
    const float* b1 = (const float*)d_in[5];
    const float* W2 = (const float*)d_in[6];
    const float* b2 = (const float*)d_in[7];
    const float* Wo = (const float*)d_in[8];
    const float* bo = (const float*)d_in[9];
    float* out = (float*)d_out;

    char* ws = (char*)d_ws;
    int* ha = (int*)(ws + 0);                // 16 KB
    short* bmean = (short*)(ws + 16384);     // 512 KB bf16 1024x256
    short* tab = (short*)(ws + 540672);      // 2 MB  bf16 4096x256
    short* W1T = (short*)(ws + 2637824);     // 512 KB bf16 512x512
    short* w2woT = (short*)(ws + 3162112);   // 256 KB bf16 256x512
    float* bfused = (float*)(ws + 3424256);  // 1 KB
    short* hbuf = (short*)(ws + 3425280);    // 4 MB  bf16 4096x512

    // 1. mega prep: W1T, w2woT, tab, ha, bfused, bucket means
    prep_kernel<<<1201, 256, 0, stream>>>(W1, Wo, W2, b2, bo, ta, tb, ka, kb,
                                          W1T, w2woT, tab, ha, bfused, bmean);
    // 2. G1: hbuf = relu([tab | bmean[ha]] @ W1 + b1)   M=4096 N=512 K=512
    mfgemm<0><<<dim3(8, 64), 256, 0, stream>>>(nullptr, W1T, tab, bmean, ha, b1,
                                               hbuf, BA, 512, 512);
    // 3. G2: out = hbuf @ w2wo + bfused                 M=4096 N=256 K=512
    mfgemm<1><<<dim3(4, 64), 256, 0, stream>>>(hbuf, w2woT, nullptr, nullptr, nullptr,
                                               bfused, out, BA, 256, 512);
}

// Round 6
// 34.858 us; speedup vs baseline: 4.6269x; 1.0168x over previous
//
#include <hip/hip_runtime.h>
#include <hip/hip_bf16.h>

#define HASH_BUCKETS 1024
#define BA 4096
#define BB 8192

typedef __attribute__((ext_vector_type(8))) short bf16x8;
typedef __attribute__((ext_vector_type(4))) float f32x4;

__device__ __forceinline__ short f2bf(float x) {
    union { float f; unsigned int u; } c;
    c.f = x;
    unsigned int lsb = (c.u >> 16) & 1u;
    c.u += 0x7fffu + lsb;  // RNE
    return (short)(c.u >> 16);
}

__device__ __forceinline__ void gl_lds16(const void* g, void* l) {
    __builtin_amdgcn_global_load_lds((const __attribute__((address_space(1))) void*)g,
                                     (__attribute__((address_space(3))) void*)l, 16, 0, 0);
}

// ================= mega prep kernel v3 =================
// blocks 0..63    : W1 (512x512 f32) -> W1T bf16 [n][k]
// blocks 64..79   : Wo (256x256 f32) -> WoT bf16 [n][c] (transpose)
// blocks 80..87   : W2 (512x256 f32) -> W2b bf16 copy
// blocks 88..151  : ta f32 -> tab bf16
// blocks 152..167 : hash_a
// block  168      : bfused = b2 @ Wo + bo (f32)
// blocks 169..1192: bucket means (1 block per bucket; self-computes hash_b)
__global__ __launch_bounds__(256) void prep_kernel(
    const float* __restrict__ W1, const float* __restrict__ Wo,
    const float* __restrict__ W2, const float* __restrict__ b2,
    const float* __restrict__ bo, const float* __restrict__ ta,
    const float* __restrict__ tb, const int* __restrict__ ka,
    const int* __restrict__ kb, short* __restrict__ W1T,
    short* __restrict__ WoT, short* __restrict__ W2b,
    short* __restrict__ tab, int* __restrict__ ha,
    float* __restrict__ bfused, short* __restrict__ bmean) {
    __shared__ __align__(16) char smem[36896];
    const int blk = blockIdx.x;
    const int t = threadIdx.x;
    if (blk < 64) {  // ---- W1T transpose ----
        float(*tl)[65] = (float(*)[65])smem;
        const int tr = (blk >> 3) * 64, tc = (blk & 7) * 64;
        const int c = t & 63, r0 = t >> 6;
#pragma unroll
        for (int i = 0; i < 16; ++i) {
            int r = r0 + i * 4;
            tl[r][c] = W1[(size_t)(tr + r) * 512 + tc + c];
        }
        __syncthreads();
#pragma unroll
        for (int i = 0; i < 16; ++i) {
            int r = r0 + i * 4;
            W1T[(size_t)(tc + r) * 512 + tr + c] = f2bf(tl[c][r]);
        }
    } else if (blk < 80) {  // ---- WoT transpose (256x256) ----
        float(*tl)[65] = (float(*)[65])smem;
        const int b = blk - 64;
        const int tr = (b >> 2) * 64, tc = (b & 3) * 64;
        const int c = t & 63, r0 = t >> 6;
#pragma unroll
        for (int i = 0; i < 16; ++i) {
            int r = r0 + i * 4;
            tl[r][c] = Wo[(size_t)(tr + r) * 256 + tc + c];
        }
        __syncthreads();
#pragma unroll
        for (int i = 0; i < 16; ++i) {
            int r = r0 + i * 4;
            WoT[(size_t)(tc + r) * 256 + tr + c] = f2bf(tl[c][r]);
        }
    } else if (blk < 88) {  // ---- W2b convert ----
        const int g = (blk - 80) * 256 + t;
#pragma unroll
        for (int i = 0; i < 16; ++i) {
            int e = g + i * 2048;
            float4 v = ((const float4*)W2)[e];
            short4 s;
            s.x = f2bf(v.x); s.y = f2bf(v.y); s.z = f2bf(v.z); s.w = f2bf(v.w);
            ((short4*)W2b)[e] = s;
        }
    } else if (blk < 152) {  // ---- tab convert ----
        const int b = blk - 88;
#pragma unroll
        for (int i = 0; i < 16; ++i) {
            int e = b * 4096 + i * 256 + t;
            float4 v = ((const float4*)ta)[e];
            short4 s;
            s.x = f2bf(v.x); s.y = f2bf(v.y); s.z = f2bf(v.z); s.w = f2bf(v.w);
            ((short4*)tab)[e] = s;
        }
    } else if (blk < 168) {  // ---- hash_a ----
        const int r = (blk - 152) * 256 + t;
        int4 k4 = ((const int4*)ka)[r];
        ha[r] = (k4.x + k4.y + k4.z + k4.w) & (HASH_BUCKETS - 1);
    } else if (blk == 168) {  // ---- bfused ----
        float acc = bo[t];
        for (int k = 0; k < 256; ++k) acc += b2[k] * Wo[(size_t)k * 256 + t];
        bfused[t] = acc;
    } else {  // ---- bucket mean: bucket h = blk-169 ----
        int* sh = (int*)smem;                  // 8192 ints
        float* part = (float*)(smem + 32768);  // 4*256 floats
        int* pcnt = (int*)(smem + 36864);      // 4 ints
        const int h = blk - 169;
        const int w = t >> 6, l = t & 63;
#pragma unroll 4
        for (int i = 0; i < 32; ++i) {
            int r = i * 256 + t;
            int4 k4 = ((const int4*)kb)[r];
            sh[r] = (k4.x + k4.y + k4.z + k4.w) & (HASH_BUCKETS - 1);
        }
        __syncthreads();
        float a0 = 0.f, a1 = 0.f, a2 = 0.f, a3 = 0.f;
        int cnt = 0;
#pragma unroll 4
        for (int it = 0; it < 32; ++it) {
            int base = w * 2048 + it * 64;
            unsigned long long m = __ballot(sh[base + l] == h);
            cnt += __popcll(m);
            while (m) {
                int j = base + (__ffsll((long long)m) - 1);
                m &= (m - 1);
                const float* row = tb + (size_t)j * 256;
                a0 += row[l];
                a1 += row[l + 64];
                a2 += row[l + 128];
                a3 += row[l + 192];
            }
        }
        part[w * 256 + l] = a0;
        part[w * 256 + l + 64] = a1;
        part[w * 256 + l + 128] = a2;
        part[w * 256 + l + 192] = a3;
        if (l == 0) pcnt[w] = cnt;
        __syncthreads();
        float s = part[t] + part[256 + t] + part[512 + t] + part[768 + t];
        int c = pcnt[0] + pcnt[1] + pcnt[2] + pcnt[3];
        bmean[(size_t)h * 256 + t] = f2bf(s / (float)max(c, 1));
    }
}

// ======== MFMA bf16 GEMM tile: 64x64, BK=64, double-buffered 2-phase pipeline ========
// LDS: [row][k16^(row&7)] both-sides XOR swizzle (gl_lds dest linear, source k
// pre-swizzled, ds_read applies same XOR) -> conflict-free b128 reads.
// MODE 0: A gathered from [tab | bmean[ha]] (K=512), +bias, ReLU, bf16 out [M][N]
// MODE 1: plain bf16 A, +bias, f32 out [M][N]
// MODE 2: plain bf16 A, no bias, bf16 out TRANSPOSED [N][M]
template <int MODE>
__device__ __forceinline__ void gemm_tile(short* __restrict__ As, short* __restrict__ Bs,
                                          const short* __restrict__ A,
                                          const short* __restrict__ Bt,
                                          const short* __restrict__ tab,
                                          const short* __restrict__ bmean,
                                          const int* __restrict__ ha,
                                          const float* __restrict__ bias,
                                          void* __restrict__ Cv,
                                          int bm, int bn, int M, int N, int K) {
    const int tid = threadIdx.x;
    const int l = tid & 63, w = tid >> 6;
    const int wm = w >> 1, wn = w & 1;

    const int r0 = (w * 2 + 0) * 8 + (l >> 3);
    const int r1 = (w * 2 + 1) * 8 + (l >> 3);
    const int sk0 = ((l & 7) ^ (r0 & 7)) * 8;
    const int sk1 = ((l & 7) ^ (r1 & 7)) * 8;
    const int arow0 = bm + r0, arow1 = bm + r1;
    const int brow0 = bn + r0, brow1 = bn + r1;
    int ha0 = 0, ha1 = 0;
    if (MODE == 0) { ha0 = ha[arow0]; ha1 = ha[arow1]; }
    const int dst0 = (w * 2 + 0) * 512;
    const int dst1 = (w * 2 + 1) * 512;

    const int lr = l & 15;
    const int g = l >> 4;
    f32x4 acc[2][2] = {};

    auto STAGE = [&](int nb, int kt) {
        const int k0 = kt * 64;
        const short *as0, *as1;
        if (MODE == 0) {
            if (k0 < 256) {
                as0 = &tab[(size_t)arow0 * 256 + k0 + sk0];
                as1 = &tab[(size_t)arow1 * 256 + k0 + sk1];
            } else {
                as0 = &bmean[(size_t)ha0 * 256 + (k0 - 256) + sk0];
                as1 = &bmean[(size_t)ha1 * 256 + (k0 - 256) + sk1];
            }
        } else {
            as0 = &A[(size_t)arow0 * K + k0 + sk0];
            as1 = &A[(size_t)arow1 * K + k0 + sk1];
        }
        gl_lds16(as0, As + nb * 4096 + dst0);
        gl_lds16(as1, As + nb * 4096 + dst1);
        gl_lds16(&Bt[(size_t)brow0 * K + k0 + sk0], Bs + nb * 4096 + dst0);
        gl_lds16(&Bt[(size_t)brow1 * K + k0 + sk1], Bs + nb * 4096 + dst1);
    };

    auto COMPUTE = [&](int nb) {
        const short* ab = As + nb * 4096;
        const short* bb = Bs + nb * 4096;
        bf16x8 af[2][2], bfr[2][2];
#pragma unroll
        for (int mf = 0; mf < 2; ++mf) {
            const int rr = wm * 32 + mf * 16 + lr;
#pragma unroll
            for (int ks = 0; ks < 2; ++ks)
                af[mf][ks] = *(const bf16x8*)&ab[rr * 64 + (((ks * 4 + g) ^ (lr & 7)) * 8)];
        }
#pragma unroll
        for (int nf = 0; nf < 2; ++nf) {
            const int rr = wn * 32 + nf * 16 + lr;
#pragma unroll
            for (int ks = 0; ks < 2; ++ks)
                bfr[nf][ks] = *(const bf16x8*)&bb[rr * 64 + (((ks * 4 + g) ^ (lr & 7)) * 8)];
        }
#pragma unroll
        for (int ks = 0; ks < 2; ++ks)
#pragma unroll
            for (int mf = 0; mf < 2; ++mf)
#pragma unroll
                for (int nf = 0; nf < 2; ++nf)
                    acc[mf][nf] = __builtin_amdgcn_mfma_f32_16x16x32_bf16(
                        af[mf][ks], bfr[nf][ks], acc[mf][nf], 0, 0, 0);
    };

    const int nt = K >> 6;
    STAGE(0, 0);
    asm volatile("s_waitcnt vmcnt(0)" ::: "memory");
    __syncthreads();
    for (int t = 0; t < nt; ++t) {
        const int cur = t & 1;
        if (t + 1 < nt) STAGE(cur ^ 1, t + 1);
        COMPUTE(cur);
        asm volatile("s_waitcnt vmcnt(0)" ::: "memory");
        __syncthreads();
    }

    // epilogue (verified mapping): D elem i -> row (l>>4)*4+i, col lr
#pragma unroll
    for (int mf = 0; mf < 2; ++mf)
#pragma unroll
        for (int nf = 0; nf < 2; ++nf) {
            const int col = bn + wn * 32 + nf * 16 + lr;
            const int rbase = bm + wm * 32 + mf * 16 + ((l >> 4) << 2);
            float bv = 0.f;
            if (MODE < 2) bv = bias[col];
#pragma unroll
            for (int i = 0; i < 4; ++i) {
                const float x = acc[mf][nf][i] + bv;
                const int row = rbase + i;
                if (MODE == 0)
                    ((short*)Cv)[(size_t)row * N + col] = f2bf(fmaxf(x, 0.f));
                else if (MODE == 1)
                    ((float*)Cv)[(size_t)row * N + col] = x;
                else
                    ((short*)Cv)[(size_t)col * M + row] = f2bf(x);
            }
        }
}

// G1 launch: y<64 -> G1 tiles (4096x512x512); y>=64 -> w2woT tiles (512x256x256)
__global__ __launch_bounds__(256) void g1_kernel(const short* __restrict__ W1T,
                                                 const short* __restrict__ tab,
                                                 const short* __restrict__ bmean,
                                                 const int* __restrict__ ha,
                                                 const float* __restrict__ b1,
                                                 short* __restrict__ hbuf,
                                                 const short* __restrict__ W2b,
                                                 const short* __restrict__ WoT,
                                                 short* __restrict__ w2woT) {
    __shared__ short As[2 * 4096];
    __shared__ short Bs[2 * 4096];
    if (blockIdx.y < 64)
        gemm_tile<0>(As, Bs, nullptr, W1T, tab, bmean, ha, b1, hbuf,
                     blockIdx.y * 64, blockIdx.x * 64, BA, 512, 512);
    else
        gemm_tile<2>(As, Bs, W2b, WoT, nullptr, nullptr, nullptr, nullptr, w2woT,
                     blockIdx.x * 64, (blockIdx.y - 64) * 64, 512, 256, 256);
}

__global__ __launch_bounds__(256) void g2_kernel(const short* __restrict__ hbuf,
                                                 const short* __restrict__ w2woT,
                                                 const float* __restrict__ bfused,
                                                 float* __restrict__ out) {
    __shared__ short As[2 * 4096];
    __shared__ short Bs[2 * 4096];
    gemm_tile<1>(As, Bs, hbuf, w2woT, nullptr, nullptr, nullptr, bfused, out,
                 blockIdx.y * 64, blockIdx.x * 64, BA, 256, 512);
}

extern "C" void kernel_launch(void* const* d_in, const int* in_sizes, int n_in,
                              void* d_out, int out_size, void* d_ws, size_t ws_size,
                              hipStream_t stream) {
    const float* ta = (const float*)d_in[0];
    const float* tb = (const float*)d_in[1];
    const int* ka = (const int*)d_in[2];
    const int* kb = (const int*)d_in[3];
    const float* W1 = (const float*)d_in[4];
    const float* b1 = (const float*)d_in[5];
    const float* W2 = (const float*)d_in[6];
    const float* b2 = (const float*)d_in[7];
    const float* Wo = (const float*)d_in[8];
    const float* bo = (const float*)d_in[9];
    float* out = (float*)d_out;

    char* ws = (char*)d_ws;
    int* ha = (int*)(ws + 0);                // 16 KB
    short* bmean = (short*)(ws + 16384);     // 512 KB bf16 1024x256
    short* tab = (short*)(ws + 540672);      // 2 MB  bf16 4096x256
    short* W1T = (short*)(ws + 2637824);     // 512 KB bf16 512x512
    short* w2woT = (short*)(ws + 3162112);   // 256 KB bf16 256x512
    float* bfused = (float*)(ws + 3424256);  // 1 KB
    short* hbuf = (short*)(ws + 3425280);    // 4 MB  bf16 4096x512
    short* WoT = (short*)(ws + 7619584);     // 128 KB bf16 256x256
    short* W2b = (short*)(ws + 7750656);     // 256 KB bf16 512x256

    // 1. prep: W1T, WoT, W2b, tab, ha, bfused, bucket means
    prep_kernel<<<1193, 256, 0, stream>>>(W1, Wo, W2, b2, bo, ta, tb, ka, kb,
                                          W1T, WoT, W2b, tab, ha, bfused, bmean);
    // 2. G1 (+ w2woT MFMA tiles): hbuf = relu([tab | bmean[ha]] @ W1 + b1)
    g1_kernel<<<dim3(8, 68), 256, 0, stream>>>(W1T, tab, bmean, ha, b1, hbuf,
                                               W2b, WoT, w2woT);
    // 3. G2: out = hbuf @ w2wo + bfused
    g2_kernel<<<dim3(4, 64), 256, 0, stream>>>(hbuf, w2woT, bfused, out);
}